// Round 4
// baseline (161.569 us; speedup 1.0000x reference)
//
#include <hip/hip_runtime.h>

// Normalized-Hermite per-dim prefactors: c_n = (2^n * n! * sqrt(pi))^{-1/2}
#define C0 0.7511255444649425f
#define C1 0.5311259660135985f
#define C2 0.2655629830067992f
#define C3 0.1084156342944575f

// Native vector type: __builtin_nontemporal_store requires ext_vector_type,
// not HIP's float4 class.
typedef float floatx4 __attribute__((ext_vector_type(4)));

// 256 threads -> 64 sites per block. Stage x (64*3 floats = 768 B) into LDS
// with 48 coalesced float4 loads, then 4 threads per site compute one
// orbital quad each and store one float4 -> fully coalesced 1 KiB/wave-store.
__global__ __launch_bounds__(256) void hermite_orbitals_kernel(
    const float* __restrict__ x, float* __restrict__ out, int nsites)
{
    __shared__ float xs[192];  // 64 sites * 3 dims

    const int t = threadIdx.x;
    const int siteBase = blockIdx.x * 64;

    // Stage: 48 threads load float4 each (768 B contiguous, 16B-aligned).
    const int totalFloats = nsites * 3;
    const int base = siteBase * 3;
    if (t < 48) {
        const int off = base + t * 4;
        if (off + 4 <= totalFloats) {
            floatx4 v = *reinterpret_cast<const floatx4*>(x + off);
            reinterpret_cast<floatx4*>(xs)[t] = v;
        } else {
            for (int k = 0; k < 4; ++k)
                xs[t * 4 + k] = (off + k < totalFloats) ? x[off + k] : 0.0f;
        }
    }
    __syncthreads();

    const int sl = t >> 2;          // local site 0..63
    const int s  = siteBase + sl;   // global site
    if (s >= nsites) return;
    const int q  = t & 3;           // orbital quad

    // Broadcast/conflict-free LDS reads (16 distinct addrs per instr, all
    // distinct mod 32 banks).
    const float x0 = xs[3 * sl + 0];
    const float x1 = xs[3 * sl + 1];
    const float x2 = xs[3 * sl + 2];

    const float t0 = x0 * x0, t1 = x1 * x1, t2 = x2 * x2;
    const float env = __expf(-0.5f * (t0 + t1 + t2));

    // Per-dim normalized Hermite values g_n = c_n * H_n(x):
    // H0=1, H1=2x, H2=4x^2-2, H3=8x^3-12x = 4x(2x^2-3)
    const float gx1 = (2.0f * C1) * x0;
    const float gx2 = C2 * (4.0f * t0 - 2.0f);

    const float gy0 = C0;
    const float gy1 = (2.0f * C1) * x1;
    const float gy2 = C2 * (4.0f * t1 - 2.0f);
    const float gy3 = (4.0f * C3) * x1 * (2.0f * t1 - 3.0f);

    const float gz0 = C0;
    const float gz1 = (2.0f * C1) * x2;
    const float gz2 = C2 * (4.0f * t2 - 2.0f);
    const float gz3 = (4.0f * C3) * x2 * (2.0f * t2 - 3.0f);

    // Fold env into x-dim factors (every product uses exactly one gx term)
    const float ex0 = env * C0;
    const float ex1 = env * gx1;
    const float ex2 = env * gx2;
    const float ex3 = env * (4.0f * C3) * x0 * (2.0f * t0 - 3.0f);

    // Orbital table (stable-sort-by-sum order of multi-indices, P=16):
    //  0:(0,0,0)  1:(0,0,1)  2:(0,1,0)  3:(1,0,0)
    //  4:(0,0,2)  5:(0,1,1)  6:(0,2,0)  7:(1,0,1)
    //  8:(1,1,0)  9:(2,0,0) 10:(0,0,3) 11:(0,1,2)
    // 12:(0,2,1) 13:(0,3,0) 14:(1,0,2) 15:(1,1,1)
    floatx4 r0, r1, r2v, r3;
    r0.x = ex0 * gy0 * gz0;   // p0
    r0.y = ex0 * gy0 * gz1;   // p1
    r0.z = ex0 * gy1 * gz0;   // p2
    r0.w = ex1 * gy0 * gz0;   // p3

    r1.x = ex0 * gy0 * gz2;   // p4
    r1.y = ex0 * gy1 * gz1;   // p5
    r1.z = ex0 * gy2 * gz0;   // p6
    r1.w = ex1 * gy0 * gz1;   // p7

    r2v.x = ex1 * gy1 * gz0;  // p8
    r2v.y = ex2 * gy0 * gz0;  // p9
    r2v.z = ex0 * gy0 * gz3;  // p10
    r2v.w = ex0 * gy1 * gz2;  // p11

    r3.x = ex0 * gy2 * gz1;   // p12
    r3.y = ex0 * gy3 * gz0;   // p13
    r3.z = ex1 * gy0 * gz2;   // p14
    r3.w = ex1 * gy1 * gz1;   // p15

    // Branchless quad select (cndmask chain; q varies within the wave)
    floatx4 r;
    r.x = q == 0 ? r0.x : (q == 1 ? r1.x : (q == 2 ? r2v.x : r3.x));
    r.y = q == 0 ? r0.y : (q == 1 ? r1.y : (q == 2 ? r2v.y : r3.y));
    r.z = q == 0 ? r0.z : (q == 1 ? r1.z : (q == 2 ? r2v.z : r3.z));
    r.w = q == 0 ? r0.w : (q == 1 ? r1.w : (q == 2 ? r2v.w : r3.w));

    // Streaming output, never re-read: nontemporal to skip L2 pollution.
    __builtin_nontemporal_store(r, reinterpret_cast<floatx4*>(out) + ((size_t)s * 4 + q));
}

extern "C" void kernel_launch(void* const* d_in, const int* in_sizes, int n_in,
                              void* d_out, int out_size, void* d_ws, size_t ws_size,
                              hipStream_t stream) {
    const float* x = (const float*)d_in[0];
    float* out = (float*)d_out;

    const int nsites = in_sizes[0] / 3;               // W * A = 2,097,152
    const int grid = (nsites + 63) / 64;              // 64 sites per 256-thread block

    hermite_orbitals_kernel<<<grid, 256, 0, stream>>>(x, out, nsites);
}